// Round 2
// baseline (412.565 us; speedup 1.0000x reference)
//
#include <hip/hip_runtime.h>
#include <math.h>

// Problem constants (fixed by the reference file)
constexpr int B = 256;
constexpr int L = 1024;
constexpr int D = 512;
constexpr int DV = D / 4;                         // 128 float4 per row
constexpr float INV_T = 0.044194173824159216f;    // 1/sqrt(512)

__global__ __launch_bounds__(1024) void cda_fused_kernel(
    const float* __restrict__ q,    // (B,1,D)
    const float* __restrict__ kc,   // (B,L,D)
    const float* __restrict__ kd,   // (B,L,D)
    const float* __restrict__ v,    // (B,L,D)
    float* __restrict__ out,        // (B,L,D)
    float* __restrict__ logits)     // (B,L)
{
    const int b    = blockIdx.x;
    const int tid  = threadIdx.x;
    const int lane = tid & 63;
    const int wave = tid >> 6;      // 0..15

    __shared__ float  s_col[L];        // col logits -> softmax weights (4 KB)
    __shared__ float  s_sig[L];        // sigmoid gates (4 KB)
    __shared__ float4 s_part[8][DV];   // partial attn accumulators (16 KB)
    __shared__ float4 s_attn[DV];      // final attn vector (2 KB)
    __shared__ float  s_redA[16];
    __shared__ float  s_redB[16];

    const int t16 = lane & 15;      // lane within 16-lane row-group
    const int sub = lane >> 4;      // row-group 0..3 within wave

    // ---- q fragment for this lane's 16-lane group: 8 float4, strided by 16 ----
    const float4* q4 = reinterpret_cast<const float4*>(q + (size_t)b * D);
    float4 qr[8];
    #pragma unroll
    for (int k = 0; k < 8; ++k) qr[k] = q4[t16 + k * 16];

    // ---- Phase 1: wave-specialized logits (waves 0-7: kc) / gates (waves 8-15: kd)
    // Each wave: 128 rows, 4 rows per iteration (16 lanes per row), 32 iterations.
    const bool isKd = (wave >= 8);
    const int  w8   = wave & 7;
    const float* src = isKd ? kd : kc;
    const float4* s4 = reinterpret_cast<const float4*>(src + (size_t)b * L * D);
    const int rbase = w8 * 128;

    #pragma unroll 2
    for (int it = 0; it < 32; ++it) {
        const int l = rbase + it * 4 + sub;
        const float4* row = s4 + (size_t)l * DV + t16;
        float a0 = 0.f, a1 = 0.f;
        #pragma unroll
        for (int k = 0; k < 8; k += 2) {
            const float4 r0 = row[k * 16];
            const float4 r1 = row[(k + 1) * 16];
            a0 += qr[k].x     * r0.x + qr[k].y     * r0.y
                + qr[k].z     * r0.z + qr[k].w     * r0.w;
            a1 += qr[k + 1].x * r1.x + qr[k + 1].y * r1.y
                + qr[k + 1].z * r1.z + qr[k + 1].w * r1.w;
        }
        float d = a0 + a1;
        d += __shfl_xor(d, 8);
        d += __shfl_xor(d, 4);
        d += __shfl_xor(d, 2);
        d += __shfl_xor(d, 1);
        if (t16 == 0) {
            if (isKd) s_sig[l] = 1.0f / (1.0f + __expf(-d * INV_T));
            else      s_col[l] = d * INV_T;
        }
    }
    __syncthreads();

    // ---- logits output (second tuple element) ----
    logits[(size_t)b * L + tid] = s_col[tid];

    // ---- Phase 2: softmax over L ----
    const float x = s_col[tid];
    float m = x;
    #pragma unroll
    for (int off = 32; off; off >>= 1) m = fmaxf(m, __shfl_xor(m, off));
    if (lane == 0) s_redA[wave] = m;
    __syncthreads();

    float gm = s_redA[0];
    #pragma unroll
    for (int i = 1; i < 16; ++i) gm = fmaxf(gm, s_redA[i]);

    const float e = __expf(x - gm);
    float ssum = e;
    #pragma unroll
    for (int off = 32; off; off >>= 1) ssum += __shfl_xor(ssum, off);
    if (lane == 0) s_redB[wave] = ssum;
    __syncthreads();

    float gs = 0.0f;
    #pragma unroll
    for (int i = 0; i < 16; ++i) gs += s_redB[i];

    s_col[tid] = e / gs;   // own element only: no race
    __syncthreads();

    // ---- Phase 3: attn[d] = sum_l w[l] * v[l,d]  (2-way accumulator split) ----
    const float4* v4 = reinterpret_cast<const float4*>(v + (size_t)b * L * D);
    const int c = tid & 127;   // float4 column
    const int g = tid >> 7;    // l-group 0..7
    float4 acc0 = make_float4(0.f, 0.f, 0.f, 0.f);
    float4 acc1 = make_float4(0.f, 0.f, 0.f, 0.f);
    #pragma unroll 4
    for (int r = 0; r < 128; r += 2) {
        const int l0 = g * 128 + r;
        const int l1 = l0 + 1;
        const float w0 = s_col[l0];
        const float w1 = s_col[l1];
        const float4 v0 = v4[(size_t)l0 * DV + c];
        const float4 v1 = v4[(size_t)l1 * DV + c];
        acc0.x += w0 * v0.x; acc0.y += w0 * v0.y;
        acc0.z += w0 * v0.z; acc0.w += w0 * v0.w;
        acc1.x += w1 * v1.x; acc1.y += w1 * v1.y;
        acc1.z += w1 * v1.z; acc1.w += w1 * v1.w;
    }
    acc0.x += acc1.x; acc0.y += acc1.y; acc0.z += acc1.z; acc0.w += acc1.w;
    s_part[g][c] = acc0;
    __syncthreads();

    if (tid < DV) {
        float4 a = s_part[0][tid];
        #pragma unroll
        for (int gg = 1; gg < 8; ++gg) {
            const float4 p = s_part[gg][tid];
            a.x += p.x; a.y += p.y; a.z += p.z; a.w += p.w;
        }
        s_attn[tid] = a;
    }
    __syncthreads();

    // ---- Phase 4: out[l,d] = sig[l] * attn[d] ----
    float4* out4 = reinterpret_cast<float4*>(out + (size_t)b * L * D);
    #pragma unroll 4
    for (int i = tid; i < L * DV; i += 1024) {
        const int l  = i >> 7;
        const int cc = i & 127;
        const float sg = s_sig[l];
        const float4 a = s_attn[cc];
        out4[i] = make_float4(sg * a.x, sg * a.y, sg * a.z, sg * a.w);
    }
}

extern "C" void kernel_launch(void* const* d_in, const int* in_sizes, int n_in,
                              void* d_out, int out_size, void* d_ws, size_t ws_size,
                              hipStream_t stream) {
    const float* q  = (const float*)d_in[0];
    const float* kc = (const float*)d_in[1];
    const float* kd = (const float*)d_in[2];
    const float* v  = (const float*)d_in[3];
    float* out    = (float*)d_out;                       // (B,L,D) flat
    float* logits = out + (size_t)B * L * D;             // (B,L) flat

    hipLaunchKernelGGL(cda_fused_kernel, dim3(B), dim3(1024), 0, stream,
                       q, kc, kd, v, out, logits);
}

// Round 3
// 408.815 us; speedup vs baseline: 1.0092x; 1.0092x over previous
//
#include <hip/hip_runtime.h>
#include <math.h>

// Problem constants (fixed by the reference file)
constexpr int B = 256;
constexpr int L = 1024;
constexpr int D = 512;
constexpr int DV = D / 4;                         // 128 float4 per row
constexpr float INV_T = 0.044194173824159216f;    // 1/sqrt(512)

// ============ K1: logits = q.kc / T ; gates = sigmoid(q.kd / T) ============
// grid = B*8 blocks, 256 threads. Block (b, rchunk) handles 128 rows.
__global__ __launch_bounds__(256) void cda_k1_logits(
    const float* __restrict__ q,
    const float* __restrict__ kc,
    const float* __restrict__ kd,
    float* __restrict__ logits,   // (B,L) in d_out tail
    float* __restrict__ gates)    // (B,L) in ws
{
    const int b      = blockIdx.x >> 3;
    const int rchunk = blockIdx.x & 7;
    const int l0     = rchunk * 128;
    const int tid    = threadIdx.x;
    const int t16    = tid & 15;
    const int grp    = tid >> 4;          // 0..15 row-groups

    __shared__ float s_log[128];
    __shared__ float s_gate[128];

    const float4* q4 = reinterpret_cast<const float4*>(q + (size_t)b * D);
    float4 qr[8];
    #pragma unroll
    for (int k = 0; k < 8; ++k) qr[k] = q4[t16 + k * 16];

    const float4* kc4 = reinterpret_cast<const float4*>(kc + (size_t)b * L * D);
    const float4* kd4 = reinterpret_cast<const float4*>(kd + (size_t)b * L * D);

    #pragma unroll 2
    for (int it = 0; it < 8; ++it) {
        const int lr = it * 16 + grp;     // row within chunk
        const int l  = l0 + lr;
        const float4* rowc = kc4 + (size_t)l * DV + t16;
        const float4* rowd = kd4 + (size_t)l * DV + t16;
        float dc = 0.f, dd = 0.f;
        #pragma unroll
        for (int k = 0; k < 8; ++k) {
            const float4 c = rowc[k * 16];
            const float4 e = rowd[k * 16];
            dc += qr[k].x * c.x + qr[k].y * c.y + qr[k].z * c.z + qr[k].w * c.w;
            dd += qr[k].x * e.x + qr[k].y * e.y + qr[k].z * e.z + qr[k].w * e.w;
        }
        dc += __shfl_xor(dc, 8); dd += __shfl_xor(dd, 8);
        dc += __shfl_xor(dc, 4); dd += __shfl_xor(dd, 4);
        dc += __shfl_xor(dc, 2); dd += __shfl_xor(dd, 2);
        dc += __shfl_xor(dc, 1); dd += __shfl_xor(dd, 1);
        if (t16 == 0) {
            s_log[lr]  = dc * INV_T;
            s_gate[lr] = 1.0f / (1.0f + __expf(-dd * INV_T));
        }
    }
    __syncthreads();

    if (tid < 128) {
        logits[(size_t)b * L + l0 + tid] = s_log[tid];
        gates [(size_t)b * L + l0 + tid] = s_gate[tid];
    }
}

// ============ K2: softmax over L, attn[d] = sum_l w_l v[l,d] ============
// grid = B blocks, 1024 threads.
__global__ __launch_bounds__(1024) void cda_k2_attn(
    const float* __restrict__ logits,
    const float* __restrict__ v,
    float* __restrict__ attn)     // (B, D) in ws
{
    const int b    = blockIdx.x;
    const int tid  = threadIdx.x;
    const int lane = tid & 63;
    const int wave = tid >> 6;

    __shared__ float  s_w[L];
    __shared__ float4 s_part[8][DV];
    __shared__ float  s_red[16];
    __shared__ float  s_red2[16];

    const float x = logits[(size_t)b * L + tid];

    float m = x;
    #pragma unroll
    for (int off = 32; off; off >>= 1) m = fmaxf(m, __shfl_xor(m, off));
    if (lane == 0) s_red[wave] = m;
    __syncthreads();
    float gm = s_red[0];
    #pragma unroll
    for (int i = 1; i < 16; ++i) gm = fmaxf(gm, s_red[i]);

    const float e = __expf(x - gm);
    float ssum = e;
    #pragma unroll
    for (int off = 32; off; off >>= 1) ssum += __shfl_xor(ssum, off);
    if (lane == 0) s_red2[wave] = ssum;
    __syncthreads();
    float gs = 0.0f;
    #pragma unroll
    for (int i = 0; i < 16; ++i) gs += s_red2[i];

    s_w[tid] = e / gs;
    __syncthreads();

    const float4* v4 = reinterpret_cast<const float4*>(v + (size_t)b * L * D);
    const int c = tid & 127;
    const int g = tid >> 7;
    float4 acc0 = make_float4(0.f, 0.f, 0.f, 0.f);
    float4 acc1 = make_float4(0.f, 0.f, 0.f, 0.f);
    #pragma unroll 4
    for (int r = 0; r < 128; r += 2) {
        const int l0 = g * 128 + r;
        const float w0 = s_w[l0];
        const float w1 = s_w[l0 + 1];
        const float4 v0 = v4[(size_t)l0 * DV + c];
        const float4 v1 = v4[(size_t)(l0 + 1) * DV + c];
        acc0.x += w0 * v0.x; acc0.y += w0 * v0.y;
        acc0.z += w0 * v0.z; acc0.w += w0 * v0.w;
        acc1.x += w1 * v1.x; acc1.y += w1 * v1.y;
        acc1.z += w1 * v1.z; acc1.w += w1 * v1.w;
    }
    acc0.x += acc1.x; acc0.y += acc1.y; acc0.z += acc1.z; acc0.w += acc1.w;
    s_part[g][c] = acc0;
    __syncthreads();

    if (tid < DV) {
        float4 a = s_part[0][tid];
        #pragma unroll
        for (int gg = 1; gg < 8; ++gg) {
            const float4 p = s_part[gg][tid];
            a.x += p.x; a.y += p.y; a.z += p.z; a.w += p.w;
        }
        reinterpret_cast<float4*>(attn)[(size_t)b * DV + tid] = a;
    }
}

// ============ K3: out[l,d] = gate[l] * attn[d] ============
// grid = B*8 blocks, 256 threads. Block (b, ochunk) writes 128 rows.
__global__ __launch_bounds__(256) void cda_k3_out(
    const float* __restrict__ gates,
    const float* __restrict__ attn,
    float* __restrict__ out)
{
    const int b      = blockIdx.x >> 3;
    const int ochunk = blockIdx.x & 7;
    const int l0     = ochunk * 128;
    const int tid    = threadIdx.x;

    __shared__ float4 s_attn[DV];
    __shared__ float  s_sig[128];

    if (tid < 128) {
        s_attn[tid] = reinterpret_cast<const float4*>(attn)[(size_t)b * DV + tid];
        s_sig[tid]  = gates[(size_t)b * L + l0 + tid];
    }
    __syncthreads();

    float4* out4 = reinterpret_cast<float4*>(out + ((size_t)b * L + l0) * D);
    #pragma unroll 4
    for (int i = tid; i < 128 * DV; i += 256) {
        const int l = i >> 7;
        const int c = i & 127;
        const float sg = s_sig[l];
        const float4 a = s_attn[c];
        out4[i] = make_float4(sg * a.x, sg * a.y, sg * a.z, sg * a.w);
    }
}

extern "C" void kernel_launch(void* const* d_in, const int* in_sizes, int n_in,
                              void* d_out, int out_size, void* d_ws, size_t ws_size,
                              hipStream_t stream) {
    const float* q  = (const float*)d_in[0];
    const float* kc = (const float*)d_in[1];
    const float* kd = (const float*)d_in[2];
    const float* v  = (const float*)d_in[3];
    float* out    = (float*)d_out;                       // (B,L,D) flat
    float* logits = out + (size_t)B * L * D;             // (B,L) flat

    float* gates = (float*)d_ws;                         // B*L floats = 1 MB
    float* attn  = gates + (size_t)B * L;                // B*D floats = 512 KB

    hipLaunchKernelGGL(cda_k1_logits, dim3(B * 8), dim3(256), 0, stream,
                       q, kc, kd, logits, gates);
    hipLaunchKernelGGL(cda_k2_attn, dim3(B), dim3(1024), 0, stream,
                       logits, v, attn);
    hipLaunchKernelGGL(cda_k3_out, dim3(B * 8), dim3(256), 0, stream,
                       gates, attn, out);
}

// Round 4
// 373.140 us; speedup vs baseline: 1.1057x; 1.0956x over previous
//
#include <hip/hip_runtime.h>
#include <math.h>

// Problem constants (fixed by the reference file)
constexpr int B = 256;
constexpr int L = 1024;
constexpr int D = 512;
constexpr int DV = D / 4;                         // 128 float4 per row
constexpr float INV_T = 0.044194173824159216f;    // 1/sqrt(512)

typedef float f4nt __attribute__((ext_vector_type(4)));
__device__ __forceinline__ void nt_store4(float4* p, float4 val) {
    __builtin_nontemporal_store(*reinterpret_cast<f4nt*>(&val),
                                reinterpret_cast<f4nt*>(p));
}

// ============ K1: logits = q.kc / T ; gates = sigmoid(q.kd / T) ============
// grid = B*8 blocks, 256 threads. Block (b, rchunk) handles 128 rows.
__global__ __launch_bounds__(256) void cda_k1_logits(
    const float* __restrict__ q,
    const float* __restrict__ kc,
    const float* __restrict__ kd,
    float* __restrict__ logits,   // (B,L) in d_out tail
    float* __restrict__ gates)    // (B,L) in ws
{
    const int b      = blockIdx.x >> 3;
    const int rchunk = blockIdx.x & 7;
    const int l0     = rchunk * 128;
    const int tid    = threadIdx.x;
    const int t16    = tid & 15;
    const int grp    = tid >> 4;          // 0..15 row-groups

    __shared__ float s_log[128];
    __shared__ float s_gate[128];

    const float4* q4 = reinterpret_cast<const float4*>(q + (size_t)b * D);
    float4 qr[8];
    #pragma unroll
    for (int k = 0; k < 8; ++k) qr[k] = q4[t16 + k * 16];

    const float4* kc4 = reinterpret_cast<const float4*>(kc + (size_t)b * L * D);
    const float4* kd4 = reinterpret_cast<const float4*>(kd + (size_t)b * L * D);

    #pragma unroll 2
    for (int it = 0; it < 8; ++it) {
        const int lr = it * 16 + grp;     // row within chunk
        const int l  = l0 + lr;
        const float4* rowc = kc4 + (size_t)l * DV + t16;
        const float4* rowd = kd4 + (size_t)l * DV + t16;
        float dc = 0.f, dd = 0.f;
        #pragma unroll
        for (int k = 0; k < 8; ++k) {
            const float4 c = rowc[k * 16];
            const float4 e = rowd[k * 16];
            dc += qr[k].x * c.x + qr[k].y * c.y + qr[k].z * c.z + qr[k].w * c.w;
            dd += qr[k].x * e.x + qr[k].y * e.y + qr[k].z * e.z + qr[k].w * e.w;
        }
        dc += __shfl_xor(dc, 8); dd += __shfl_xor(dd, 8);
        dc += __shfl_xor(dc, 4); dd += __shfl_xor(dd, 4);
        dc += __shfl_xor(dc, 2); dd += __shfl_xor(dd, 2);
        dc += __shfl_xor(dc, 1); dd += __shfl_xor(dd, 1);
        if (t16 == 0) {
            s_log[lr]  = dc * INV_T;
            s_gate[lr] = 1.0f / (1.0f + __expf(-dd * INV_T));
        }
    }
    __syncthreads();

    if (tid < 128) {
        logits[(size_t)b * L + l0 + tid] = s_log[tid];
        gates [(size_t)b * L + l0 + tid] = s_gate[tid];
    }
}

// ============ K2: softmax over L, partial attn over 256 rows of v ============
// grid = B*4 blocks, 512 threads. Block (b, quarter): rows [q*256, q*256+256).
// Softmax over the full L computed redundantly per block (4 KB read - free).
__global__ __launch_bounds__(512) void cda_k2_attn(
    const float* __restrict__ logits,
    const float* __restrict__ v,
    float* __restrict__ attn_part)    // (B, 4, D) in ws
{
    const int b       = blockIdx.x >> 2;
    const int quarter = blockIdx.x & 3;
    const int tid     = threadIdx.x;
    const int lane    = tid & 63;
    const int wave    = tid >> 6;     // 0..7

    __shared__ float  s_w[L];
    __shared__ float4 s_part[4][DV];
    __shared__ float  s_red[8];
    __shared__ float  s_red2[8];

    const float x0 = logits[(size_t)b * L + tid];
    const float x1 = logits[(size_t)b * L + tid + 512];

    float m = fmaxf(x0, x1);
    #pragma unroll
    for (int off = 32; off; off >>= 1) m = fmaxf(m, __shfl_xor(m, off));
    if (lane == 0) s_red[wave] = m;
    __syncthreads();
    float gm = s_red[0];
    #pragma unroll
    for (int i = 1; i < 8; ++i) gm = fmaxf(gm, s_red[i]);

    const float e0 = __expf(x0 - gm);
    const float e1 = __expf(x1 - gm);
    float ssum = e0 + e1;
    #pragma unroll
    for (int off = 32; off; off >>= 1) ssum += __shfl_xor(ssum, off);
    if (lane == 0) s_red2[wave] = ssum;
    __syncthreads();
    float gs = 0.0f;
    #pragma unroll
    for (int i = 0; i < 8; ++i) gs += s_red2[i];
    const float rgs = 1.0f / gs;

    s_w[tid]       = e0 * rgs;
    s_w[tid + 512] = e1 * rgs;
    __syncthreads();

    // partial attn: rows [quarter*256, quarter*256+256), 4 groups x 64 rows
    const float4* v4 = reinterpret_cast<const float4*>(v + (size_t)b * L * D);
    const int c = tid & 127;          // float4 column
    const int g = tid >> 7;           // 0..3
    const int lbase = quarter * 256 + g * 64;
    float4 acc0 = make_float4(0.f, 0.f, 0.f, 0.f);
    float4 acc1 = make_float4(0.f, 0.f, 0.f, 0.f);
    #pragma unroll 4
    for (int r = 0; r < 64; r += 2) {
        const int l0 = lbase + r;
        const float w0 = s_w[l0];
        const float w1 = s_w[l0 + 1];
        const float4 v0 = v4[(size_t)l0 * DV + c];
        const float4 v1 = v4[(size_t)(l0 + 1) * DV + c];
        acc0.x += w0 * v0.x; acc0.y += w0 * v0.y;
        acc0.z += w0 * v0.z; acc0.w += w0 * v0.w;
        acc1.x += w1 * v1.x; acc1.y += w1 * v1.y;
        acc1.z += w1 * v1.z; acc1.w += w1 * v1.w;
    }
    acc0.x += acc1.x; acc0.y += acc1.y; acc0.z += acc1.z; acc0.w += acc1.w;
    s_part[g][c] = acc0;
    __syncthreads();

    if (tid < DV) {
        const float4 p0 = s_part[0][tid];
        const float4 p1 = s_part[1][tid];
        const float4 p2 = s_part[2][tid];
        const float4 p3 = s_part[3][tid];
        float4 a;
        a.x = (p0.x + p1.x) + (p2.x + p3.x);
        a.y = (p0.y + p1.y) + (p2.y + p3.y);
        a.z = (p0.z + p1.z) + (p2.z + p3.z);
        a.w = (p0.w + p1.w) + (p2.w + p3.w);
        reinterpret_cast<float4*>(attn_part)[((size_t)b * 4 + quarter) * DV + tid] = a;
    }
}

// ============ K3: out[l,d] = gate[l] * (sum of 4 attn partials)[d] ============
// grid = B*8 blocks, 256 threads. Block (b, ochunk) writes 128 rows (NT stores).
__global__ __launch_bounds__(256) void cda_k3_out(
    const float* __restrict__ gates,
    const float* __restrict__ attn_part,
    float* __restrict__ out)
{
    const int b      = blockIdx.x >> 3;
    const int ochunk = blockIdx.x & 7;
    const int l0     = ochunk * 128;
    const int tid    = threadIdx.x;

    __shared__ float4 s_attn[DV];
    __shared__ float  s_sig[128];

    if (tid < 128) {
        const float4* ap = reinterpret_cast<const float4*>(attn_part);
        const float4 p0 = ap[((size_t)b * 4 + 0) * DV + tid];
        const float4 p1 = ap[((size_t)b * 4 + 1) * DV + tid];
        const float4 p2 = ap[((size_t)b * 4 + 2) * DV + tid];
        const float4 p3 = ap[((size_t)b * 4 + 3) * DV + tid];
        float4 a;
        a.x = (p0.x + p1.x) + (p2.x + p3.x);
        a.y = (p0.y + p1.y) + (p2.y + p3.y);
        a.z = (p0.z + p1.z) + (p2.z + p3.z);
        a.w = (p0.w + p1.w) + (p2.w + p3.w);
        s_attn[tid] = a;
        s_sig[tid]  = gates[(size_t)b * L + l0 + tid];
    }
    __syncthreads();

    float4* out4 = reinterpret_cast<float4*>(out + ((size_t)b * L + l0) * D);
    #pragma unroll 4
    for (int i = tid; i < 128 * DV; i += 256) {
        const int l = i >> 7;
        const int c = i & 127;
        const float sg = s_sig[l];
        const float4 a = s_attn[c];
        nt_store4(&out4[i], make_float4(sg * a.x, sg * a.y, sg * a.z, sg * a.w));
    }
}

extern "C" void kernel_launch(void* const* d_in, const int* in_sizes, int n_in,
                              void* d_out, int out_size, void* d_ws, size_t ws_size,
                              hipStream_t stream) {
    const float* q  = (const float*)d_in[0];
    const float* kc = (const float*)d_in[1];
    const float* kd = (const float*)d_in[2];
    const float* v  = (const float*)d_in[3];
    float* out    = (float*)d_out;                       // (B,L,D) flat
    float* logits = out + (size_t)B * L * D;             // (B,L) flat

    float* gates     = (float*)d_ws;                     // B*L floats   = 1 MB
    float* attn_part = gates + (size_t)B * L;            // B*4*D floats = 2 MB

    hipLaunchKernelGGL(cda_k1_logits, dim3(B * 8), dim3(256), 0, stream,
                       q, kc, kd, logits, gates);
    hipLaunchKernelGGL(cda_k2_attn, dim3(B * 4), dim3(512), 0, stream,
                       logits, v, attn_part);
    hipLaunchKernelGGL(cda_k3_out, dim3(B * 8), dim3(256), 0, stream,
                       gates, attn_part, out);
}